// Round 5
// baseline (151.395 us; speedup 1.0000x reference)
//
#include <hip/hip_runtime.h>
#include <hip/hip_bf16.h>

// out[b,t] = cumsum_t( relu(x @ Wh^T + bh) ) + (x @ Wb + bb)
// B=16384, D=1024, T=512. fp32 in/out; GEMM in bf16 MFMA (fp32 accum).
// R4 (resubmit; R4 bench was an infra timeout): 3-deep pipeline. 8 waves
// (512thr), wave tile 64x64 (min LDS frag traffic). BK=32, triple-buffered
// LDS (108KB), counted vmcnt(12): tiles t+1,t+2 DMA stay in flight across
// barriers -> DMA has 2 full iters to land.

typedef __bf16 bf16x8 __attribute__((ext_vector_type(8)));
typedef __bf16 bf16x4 __attribute__((ext_vector_type(4)));
typedef float f32x4 __attribute__((ext_vector_type(4)));

typedef const __attribute__((address_space(1))) void* gas_cptr;
typedef __attribute__((address_space(3))) void* las_ptr;

#define BM 64
#define BK 32     // elements; 64 B per LDS row
#define NKIT 32   // 1024/32
#define TDIM 512
#define DDIM 1024
#define ASZ (BM * 64)     // 4 KB per buffer
#define BSZ (TDIM * 64)   // 32 KB per buffer

#define WAITV12()  asm volatile("s_waitcnt vmcnt(12) lgkmcnt(0)" ::: "memory")
#define WAITV6()   asm volatile("s_waitcnt vmcnt(6) lgkmcnt(0)"  ::: "memory")
#define WAITV0()   asm volatile("s_waitcnt vmcnt(0) lgkmcnt(0)"  ::: "memory")
#define WAIT_LGKM() asm volatile("s_waitcnt lgkmcnt(0)" ::: "memory")
#define SBAR()     __builtin_amdgcn_s_barrier()

// ---- kernel 1: Wh fp32 -> bf16 ----
__global__ __launch_bounds__(256) void cvt_wh_kernel(const float* __restrict__ src,
                                                     __bf16* __restrict__ dst) {
    const int i = (blockIdx.x * 256 + threadIdx.x) * 4;
    const float4 v = *reinterpret_cast<const float4*>(src + i);
    bf16x4 o;
    o[0] = (__bf16)v.x; o[1] = (__bf16)v.y; o[2] = (__bf16)v.z; o[3] = (__bf16)v.w;
    *reinterpret_cast<bf16x4*>(dst + i) = o;
}

// XOR-swizzle of 16B granule within a 64B row: 2-way banks on b128 frag reads (free)
__device__ __forceinline__ int swz64(int row) { return ((row >> 1) & 3) << 4; }

// ---- kernel 2: fused GEMM + bias + relu + row-cumsum + base ----
__global__ __launch_bounds__(512, 2) void survival_kernel(
    const float* __restrict__ x,      // [16384][1024] fp32
    const __bf16* __restrict__ Whb,   // [512][1024] bf16
    const float* __restrict__ bh,     // [512]
    const float* __restrict__ Wb,     // [1024]
    const float* __restrict__ bbp,    // [1]
    float* __restrict__ out)          // [16384][512] fp32
{
    __shared__ __align__(16) char Alds[3][ASZ];   // 12 KB
    __shared__ __align__(16) char Blds[3][BSZ];   // 96 KB
    __shared__ float baseLds[BM];
    __shared__ float totLds[BM][8];

    const int tid  = threadIdx.x;
    const int lane = tid & 63;
    const int wid  = tid >> 6;   // 0..7 : wave owns cols wid*64..+63, ALL 64 rows
    const int brow = blockIdx.x * BM;
    const float bb0 = bbp[0];

    // --- A staging map: row = tid>>3 (0..63), chunk = tid&7 (4 fp32 = 8B bf16) ---
    const int ar = tid >> 3;
    const int ac = tid & 7;
    const float* xrow = x + (size_t)(brow + ar) * DDIM + ac * 4;
    const float* wbp  = Wb + ac * 4;
    const int a_off = ar * 64 + (((ac >> 1) * 16) ^ swz64(ar)) + (ac & 1) * 8;

    // --- B staging: per wave 4 DMA of 1KB (16 rows); row = base + lane>>2 ---
    const int b_rbase = wid * 64 + (lane >> 2);
    const int b_slot  = lane & 3;

    float bpart = 0.f;
    f32x4 acc[4][4];
#pragma unroll
    for (int rt = 0; rt < 4; ++rt)
#pragma unroll
        for (int n = 0; n < 4; ++n)
            acc[rt][n] = (f32x4){0.f, 0.f, 0.f, 0.f};

    float4 xr0, wr0, xr1, wr1;   // A-reg double slots (static under full unroll)

    // issue order per tile: A-loads FIRST, then B-DMA (so consuming A regs
    // mid-iter never forces the next tile's B-DMA to drain).
    auto issueT = [&](int buf, int it, int slot) {
        const int k0 = it * BK;
        if (slot == 0) { xr0 = *reinterpret_cast<const float4*>(xrow + k0);
                         wr0 = *reinterpret_cast<const float4*>(wbp + k0); }
        else           { xr1 = *reinterpret_cast<const float4*>(xrow + k0);
                         wr1 = *reinterpret_cast<const float4*>(wbp + k0); }
#pragma unroll
        for (int c = 0; c < 4; ++c) {
            const int row  = b_rbase + c * 16;
            const int colb = (b_slot * 16) ^ swz64(row);
            const __bf16* g = Whb + (size_t)row * DDIM + k0 + (colb >> 1);
            char* l = &Blds[buf][0] + (wid * 64 + c * 16) * 64;  // wave-uniform base
            __builtin_amdgcn_global_load_lds((gas_cptr)(const void*)g,
                                             (las_ptr)(void*)l, 16, 0, 0);
        }
    };

    auto writeT = [&](int buf, int slot) {
        const float4 xv = slot ? xr1 : xr0;
        const float4 wv = slot ? wr1 : wr0;
        bpart += xv.x * wv.x + xv.y * wv.y + xv.z * wv.z + xv.w * wv.w;
        bf16x4 av;
        av[0] = (__bf16)xv.x; av[1] = (__bf16)xv.y;
        av[2] = (__bf16)xv.z; av[3] = (__bf16)xv.w;
        *reinterpret_cast<bf16x4*>(&Alds[buf][0] + a_off) = av;
    };

    auto compute = [&](int buf) {
        const char* Ab = &Alds[buf][0];
        const char* Bb = &Blds[buf][0];
        const int qslot = (lane >> 4) * 16;   // k-quarter byte slot
        bf16x8 af[4];
#pragma unroll
        for (int rt = 0; rt < 4; ++rt) {
            const int row = rt * 16 + (lane & 15);
            af[rt] = *reinterpret_cast<const bf16x8*>(Ab + row * 64 + (qslot ^ swz64(row)));
        }
#pragma unroll
        for (int n = 0; n < 4; ++n) {
            const int trow = wid * 64 + n * 16 + (lane & 15);
            const bf16x8 bfr = *reinterpret_cast<const bf16x8*>(
                Bb + trow * 64 + (qslot ^ swz64(trow)));
#pragma unroll
            for (int rt = 0; rt < 4; ++rt)
                acc[rt][n] = __builtin_amdgcn_mfma_f32_16x16x32_bf16(af[rt], bfr, acc[rt][n], 0, 0, 0);
        }
    };

    // --- prologue: tiles 0 and 1 in flight; A[0] written to LDS ---
    issueT(0, 0, 0);
    issueT(1, 1, 1);
    writeT(0, 0);       // compiler waits A[0] loads only (B[0] stays in flight)

    // --- 3-deep pipelined K loop (fully unrolled: static %3/%2 indices) ---
#pragma unroll
    for (int t = 0; t < NKIT; ++t) {
        if (t + 2 < NKIT) issueT((t + 2) % 3, t + 2, t & 1);
        if (t + 2 < NKIT)      WAITV12();   // tiles t+1,t+2 (12 ops) stay in flight
        else if (t + 1 < NKIT) WAITV6();
        else                   WAITV0();
        SBAR();                              // tile t fully in LDS, A[t] visible
        compute(t % 3);
        if (t + 1 < NKIT) writeT((t + 1) % 3, (t + 1) & 1);
        WAIT_LGKM();                         // my frag reads + A-write drained
        SBAR();                              // buffer (t%3) now reusable
    }

    // --- base = x@Wb + bb : reduce 8 chunk-partials per row ---
    bpart += __shfl_xor(bpart, 1, 8);
    bpart += __shfl_xor(bpart, 2, 8);
    bpart += __shfl_xor(bpart, 4, 8);
    if (ac == 0) baseLds[ar] = bpart + bb0;

    // --- epilogue: bias + relu + in-register inclusive scan over T ---
    // C layout (m89): col = lane&15, row = (lane>>4)*4 + j within 16x16 tile
    float bhv[4];
#pragma unroll
    for (int n = 0; n < 4; ++n)
        bhv[n] = bh[wid * 64 + n * 16 + (lane & 15)];

    float carry[4][4];
#pragma unroll
    for (int rt = 0; rt < 4; ++rt)
#pragma unroll
        for (int j = 0; j < 4; ++j) carry[rt][j] = 0.f;

#pragma unroll
    for (int n = 0; n < 4; ++n) {
#pragma unroll
        for (int rt = 0; rt < 4; ++rt) {
#pragma unroll
            for (int j = 0; j < 4; ++j) {
                float v = fmaxf(acc[rt][n][j] + bhv[n], 0.f);
#pragma unroll
                for (int off = 1; off < 16; off <<= 1) {
                    const float u = __shfl_up(v, (unsigned)off, 16);
                    if ((lane & 15) >= off) v += u;
                }
                v += carry[rt][j];
                carry[rt][j] = __shfl(v, 15, 16);
                acc[rt][n][j] = v;
            }
        }
    }

    // per-row 64-col chunk totals -> LDS for cross-wave carry
    if ((lane & 15) == 0) {
#pragma unroll
        for (int rt = 0; rt < 4; ++rt)
#pragma unroll
            for (int j = 0; j < 4; ++j) {
                const int r = rt * 16 + (lane >> 4) * 4 + j;
                totLds[r][wid] = carry[rt][j];
            }
    }
    __syncthreads();

#pragma unroll
    for (int rt = 0; rt < 4; ++rt) {
#pragma unroll
        for (int j = 0; j < 4; ++j) {
            const int r = rt * 16 + (lane >> 4) * 4 + j;
            float rc = baseLds[r];
#pragma unroll
            for (int w = 0; w < 7; ++w)
                if (w < wid) rc += totLds[r][w];
            float* orow = out + (size_t)(brow + r) * TDIM + wid * 64 + (lane & 15);
#pragma unroll
            for (int n = 0; n < 4; ++n)
                orow[n * 16] = acc[rt][n][j] + rc;
        }
    }
}

extern "C" void kernel_launch(void* const* d_in, const int* in_sizes, int n_in,
                              void* d_out, int out_size, void* d_ws, size_t ws_size,
                              hipStream_t stream) {
    const float* x  = (const float*)d_in[0];
    const float* Wh = (const float*)d_in[1];
    const float* bh = (const float*)d_in[2];
    const float* Wb = (const float*)d_in[3];
    const float* bb = (const float*)d_in[4];
    float* out = (float*)d_out;
    __bf16* Whb = (__bf16*)d_ws;              // 1 MB scratch

    cvt_wh_kernel<<<512, 256, 0, stream>>>(Wh, Whb);
    survival_kernel<<<256, 512, 0, stream>>>(x, Whb, bh, Wb, bb, out);
}